// Round 13
// baseline (86.844 us; speedup 1.0000x reference)
//
#include <hip/hip_runtime.h>
#include <math.h>

#define BB 512
#define LL 4096
#define MAXLAG 20
#define NLAGS 41
#define TAU 0.05f
#define NT 512
#define CHUNK 8

// Padded LDS layout (proven r7/r10): element i (i in [-32,4128)) -> ip=i+32,
// fi = ip + 4*(ip>>3) (4 pad floats per 8 data floats). Thread t owns 8t..8t+7:
// fi = 12t + fo(x), fo(x)=(x+32)+4*((x+32)>>3). Lane stride 48 B -> conflict-free b128.

// ---- DPP adds ----
template<int CTRL, int RM, int BM, bool BC>
__device__ __forceinline__ float dpp_add(float x) {
    const int t = __builtin_amdgcn_update_dpp(0, __float_as_int(x), CTRL, RM, BM, BC);
    return x + __int_as_float(t);
}
// full 64-lane sum; result in lane 63
__device__ __forceinline__ float wave_sum63(float x) {
    x = dpp_add<0x111, 0xf, 0xf, true >(x);  // row_shr:1
    x = dpp_add<0x112, 0xf, 0xf, true >(x);  // row_shr:2
    x = dpp_add<0x114, 0xf, 0xf, true >(x);  // row_shr:4
    x = dpp_add<0x118, 0xf, 0xf, true >(x);  // row_shr:8
    x = dpp_add<0x142, 0xa, 0xf, false>(x);  // row_bcast:15
    x = dpp_add<0x143, 0xc, 0xf, false>(x);  // row_bcast:31 -> lane63 total
    return x;
}
// 16-lane row sum; result in lane 15 of each row
__device__ __forceinline__ float row_sum15(float x) {
    x = dpp_add<0x111, 0xf, 0xf, true >(x);
    x = dpp_add<0x112, 0xf, 0xf, true >(x);
    x = dpp_add<0x114, 0xf, 0xf, true >(x);
    x = dpp_add<0x118, 0xf, 0xf, true >(x);
    return x;
}

struct SmemT {
    float redPG[32][NLAGS];       // 32 row-partials per lag
    float edges[10][MAXLAG + 1];  // 0:prefP 1:prefPP 2:prefG 3:prefGG (4 unused)
                                  // 5:sufP  6:sufPP  7:sufG  8:sufGG  (9 unused)
    float wsums[8][4];
    float l1part[32];
    float best_pcc, zero_pcc, pen;
    int best_il;
    int amLast;
};

// one lag group: lags L0 .. L0+G-1 (L0 % 4 == 0); computes only spg
template<int L0, int G>
__device__ __forceinline__ void lag_group(const float* __restrict__ lds_p,
                                          const float (&gr)[CHUNK],
                                          SmemT& sm, int tid, bool isTail) {
    constexpr int NW4 = (G + CHUNK + 2) / 4;   // G=8 -> 4 float4, G=1 -> 2
    float pw[NW4 * 4];
    const int pbase = 12 * tid;
    #pragma unroll
    for (int k = 0; k < NW4; ++k) {
        const int x32 = L0 + 4 * k + 32;       // >= 12, mult of 4
        const int fo = x32 + 4 * (x32 >> 3);
        const float4 w = *(const float4*)&lds_p[pbase + fo];
        pw[4 * k + 0] = w.x; pw[4 * k + 1] = w.y;
        pw[4 * k + 2] = w.z; pw[4 * k + 3] = w.w;
    }
    #pragma unroll
    for (int dl = 0; dl < G; ++dl) {
        float s0 = 0.f, s1 = 0.f;
        #pragma unroll
        for (int k = 0; k < CHUNK; k += 2) {
            s0 = fmaf(pw[dl + k],     gr[k],     s0);
            s1 = fmaf(pw[dl + k + 1], gr[k + 1], s1);
        }
        const float spg = row_sum15(s0 + s1);
        if (isTail) sm.redPG[tid >> 4][L0 + MAXLAG + dl] = spg;
    }
}

__global__ __launch_bounds__(NT, 4) void lagloss_kernel(const float* __restrict__ pred,
                                                        const float* __restrict__ gt,
                                                        float4* __restrict__ ws,
                                                        int* __restrict__ cnt,
                                                        float* __restrict__ out) {
    __shared__ float lds_p[6240];
    __shared__ float lds_g[6240];
    __shared__ SmemT sm;

    const int b = blockIdx.x;
    const int tid = threadIdx.x;
    const int wid = tid >> 6;
    const int lane = tid & 63;
    const float* __restrict__ prow = pred + (size_t)b * LL;
    const float* __restrict__ grow = gt + (size_t)b * LL;

    // ---- zero the pads: ip in [0,32) and [4128,4160) for both buffers ----
    if (tid < 32) {
        const int m = tid & 7;
        const int ip = ((tid & 8) ? 4128 : 0) + 4 * m;
        const int fi = ip + 4 * (ip >> 3);
        float* buf = (tid < 16) ? lds_p : lds_g;
        *(float4*)&buf[fi] = float4{0.f, 0.f, 0.f, 0.f};
    }

    // ---- stage rows into padded LDS (dense 16B-stride coalesced) + row sums ----
    const int wb = 4 * tid + 32 + 4 * ((tid + 8) >> 1);
    float ap = 0.f, ag = 0.f, app = 0.f, agg = 0.f;
    #pragma unroll
    for (int it = 0; it < 2; ++it) {
        const int j = tid + NT * it;
        const float4 p4 = ((const float4*)prow)[j];
        const float4 g4 = ((const float4*)grow)[j];
        *(float4*)&lds_p[wb + 3072 * it] = p4;
        *(float4*)&lds_g[wb + 3072 * it] = g4;
        ap += p4.x + p4.y + p4.z + p4.w;
        ag += g4.x + g4.y + g4.z + g4.w;
        app = fmaf(p4.x, p4.x, fmaf(p4.y, p4.y, fmaf(p4.z, p4.z, fmaf(p4.w, p4.w, app))));
        agg = fmaf(g4.x, g4.x, fmaf(g4.y, g4.y, fmaf(g4.z, g4.z, fmaf(g4.w, g4.w, agg))));
    }
    ap = wave_sum63(ap); ag = wave_sum63(ag);
    app = wave_sum63(app); agg = wave_sum63(agg);
    if (lane == 63) {
        sm.wsums[wid][0] = ap; sm.wsums[wid][1] = ag;
        sm.wsums[wid][2] = app; sm.wsums[wid][3] = agg;
    }
    __syncthreads();

    // ---- edge prefix/suffix sums: 168 workers, each <=20 independent LDS loads ----
    if (tid < 8 * (MAXLAG + 1)) {
        const int aa = tid / (MAXLAG + 1);
        const int k = tid % (MAXLAG + 1);
        const int a = (aa < 4) ? aa : aa + 1;   // {0,1,2,3,5,6,7,8}
        const int m = a % 5;
        const bool useG = (m >= 2);
        const bool bwd = (a >= 5);
        const bool opSq = (m & 1);
        const float* buf = useG ? lds_g : lds_p;
        float s = 0.f;
        #pragma unroll
        for (int i = 0; i < MAXLAG; ++i) {
            if (i < k) {
                const int idx = bwd ? (LL - 1 - i) : i;
                const int ip = idx + 32;
                const float x = buf[ip + 4 * (ip >> 3)];
                s += opSq ? x * x : x;
            }
        }
        sm.edges[a][k] = s;
    }

    // ---- g chunk into registers ----
    float gr[CHUNK];
    {
        const int gbase = 12 * tid;
        const float4 a = *(const float4*)&lds_g[gbase + 48];  // fo(0)
        const float4 c = *(const float4*)&lds_g[gbase + 52];  // fo(4)
        gr[0] = a.x; gr[1] = a.y; gr[2] = a.z; gr[3] = a.w;
        gr[4] = c.x; gr[5] = c.y; gr[6] = c.z; gr[7] = c.w;
    }
    const bool isTail = ((tid & 15) == 15);

    // ---- 41 lags: spg only, pure-register inner math, short DPP chains ----
    lag_group<-20, 8>(lds_p, gr, sm, tid, isTail);
    lag_group<-12, 8>(lds_p, gr, sm, tid, isTail);
    lag_group< -4, 8>(lds_p, gr, sm, tid, isTail);
    lag_group<  4, 8>(lds_p, gr, sm, tid, isTail);
    lag_group< 12, 8>(lds_p, gr, sm, tid, isTail);
    lag_group< 20, 1>(lds_p, gr, sm, tid, isTail);
    __syncthreads();

    // ---- wave 0: pcc (register-resident) + argmax + softmax, one phase ----
    if (wid == 0) {
        float v = -3.0f;
        if (lane < NLAGS) {
            const int il = lane;
            const int l = il - MAXLAG;
            const int m = l < 0 ? -l : l;
            const float fn = (float)(LL - m);
            float spg = 0.f;
            #pragma unroll
            for (int r = 0; r < 32; ++r) spg += sm.redPG[r][il];
            float Sp = 0.f, Sg = 0.f, Spp = 0.f, Sgg = 0.f;
            #pragma unroll
            for (int w = 0; w < 8; ++w) {
                Sp += sm.wsums[w][0]; Sg += sm.wsums[w][1];
                Spp += sm.wsums[w][2]; Sgg += sm.wsums[w][3];
            }
            float Spw, Sgw, Sppw, Sggw;
            if (l >= 0) {
                Spw  = Sp  - sm.edges[0][m];
                Sppw = Spp - sm.edges[1][m];
                Sgw  = Sg  - sm.edges[7][m];
                Sggw = Sgg - sm.edges[8][m];
            } else {
                Spw  = Sp  - sm.edges[5][m];
                Sppw = Spp - sm.edges[6][m];
                Sgw  = Sg  - sm.edges[2][m];
                Sggw = Sgg - sm.edges[3][m];
            }
            const float num  = spg - Spw * Sgw / fn;
            const float varp = Sppw - Spw * Spw / fn;
            const float varg = Sggw - Sgw * Sgw / fn;
            const float den2 = fmaxf(varp * varg, 1e-12f);
            v = num / sqrtf(den2);
        }
        float bv = v;
        int bi = lane;
        #pragma unroll
        for (int d = 32; d; d >>= 1) {
            const float ov = __shfl_xor(bv, d, 64);
            const int oi = __shfl_xor(bi, d, 64);
            if (ov > bv || (ov == bv && oi < bi)) { bv = ov; bi = oi; }
        }
        const float zp = __shfl(v, MAXLAG, 64);
        const float e = (lane < NLAGS) ? __expf((v - bv) * (1.0f / TAU)) : 0.0f;
        const float lc = (lane < NLAGS) ? fabsf((float)(lane - MAXLAG)) * (1.0f / MAXLAG) : 0.0f;
        float wsum = e, psum = e * lc;
        #pragma unroll
        for (int d = 32; d; d >>= 1) {
            wsum += __shfl_xor(wsum, d, 64);
            psum += __shfl_xor(psum, d, 64);
        }
        if (lane == 0) {
            sm.best_pcc = bv;
            sm.best_il = bi;
            sm.zero_pcc = zp;
            sm.pen = psum / wsum;
        }
    }
    __syncthreads();

    // ---- L1 for the single best lag: masked pass over own chunk ----
    {
        const int bl = sm.best_il - MAXLAG;
        const int c0 = tid * CHUNK;
        float sab = 0.f;
        #pragma unroll
        for (int k = 0; k < CHUNK; ++k) {
            const int pi = c0 + k + bl;
            const int ip = pi + 32;
            const float p = lds_p[ip + 4 * (ip >> 3)];  // pads are zero
            const float d = fabsf(p - gr[k]);
            sab += (pi >= 0 && pi < LL) ? d : 0.f;
        }
        sab = row_sum15(sab);
        if (isTail) sm.l1part[tid >> 4] = sab;
    }
    __syncthreads();

    // ---- per-block scalars -> workspace (plain store, no atomics) ----
    if (tid == 0) {
        const int bl = sm.best_il - MAXLAG;
        const int m = bl < 0 ? -bl : bl;
        float sab = 0.f;
        #pragma unroll
        for (int r = 0; r < 32; ++r) sab += sm.l1part[r];
        const float l1 = sab / (float)(LL - m);
        ws[b] = float4{1.0f - sm.best_pcc, l1, 1.0f - sm.zero_pcc, sm.pen};
    }

    // ---- last-block-done reduction: ticket 511 reduces ws -> out ----
    __threadfence();                       // release: make ws[b] visible device-wide
    if (tid == 0) {
        const int t = atomicAdd(cnt, 1);   // device-scope by default on gfx950
        sm.amLast = (t == BB - 1);
    }
    __syncthreads();
    if (sm.amLast) {
        __threadfence();                   // acquire: see all other blocks' ws stores
        __shared__ float4 part[8];
        const float4 v4 = ws[tid];
        const float x = wave_sum63(v4.x);
        const float y = wave_sum63(v4.y);
        const float z = wave_sum63(v4.z);
        const float w = wave_sum63(v4.w);
        if (lane == 63) part[wid] = float4{x, y, z, w};
        __syncthreads();
        if (tid == 0) {
            float s0 = 0.f, s1 = 0.f, s2 = 0.f, s3 = 0.f;
            #pragma unroll
            for (int i = 0; i < 8; ++i) {
                s0 += part[i].x; s1 += part[i].y; s2 += part[i].z; s3 += part[i].w;
            }
            const float inv = 1.0f / (float)BB;
            out[0] = s0 * inv;
            out[1] = s1 * inv;
            out[2] = s2 * inv;
            out[3] = s3 * inv;
        }
    }
}

extern "C" void kernel_launch(void* const* d_in, const int* in_sizes, int n_in,
                              void* d_out, int out_size, void* d_ws, size_t ws_size,
                              hipStream_t stream) {
    const float* pred = (const float*)d_in[0];
    const float* gt   = (const float*)d_in[1];
    float* out = (float*)d_out;
    float4* ws = (float4*)d_ws;
    int* cnt = (int*)((char*)d_ws + BB * sizeof(float4));

    hipMemsetAsync(cnt, 0, sizeof(int), stream);   // graph-capturable, sub-us
    lagloss_kernel<<<BB, NT, 0, stream>>>(pred, gt, ws, cnt, out);
}

// Round 14
// 15.261 us; speedup vs baseline: 5.6907x; 5.6907x over previous
//
#include <hip/hip_runtime.h>
#include <math.h>

#define BB 512
#define LL 4096
#define MAXLAG 20
#define NLAGS 41
#define TAU 0.05f
#define NT 512
#define CHUNK 8

// Padded LDS layout (proven r7): element i (i in [-32,4128)) -> ip=i+32,
// fi = ip + 4*(ip>>3) (4 pad floats per 8 data floats). Thread t owns 8t..8t+7:
// fi = 12t + fo(x), fo(x)=(x+32)+4*((x+32)>>3). Lane stride 48 B -> conflict-free b128.

// ---- DPP adds ----
template<int CTRL, int RM, int BM, bool BC>
__device__ __forceinline__ float dpp_add(float x) {
    const int t = __builtin_amdgcn_update_dpp(0, __float_as_int(x), CTRL, RM, BM, BC);
    return x + __int_as_float(t);
}
// full 64-lane sum; result in lane 63
__device__ __forceinline__ float wave_sum63(float x) {
    x = dpp_add<0x111, 0xf, 0xf, true >(x);  // row_shr:1
    x = dpp_add<0x112, 0xf, 0xf, true >(x);  // row_shr:2
    x = dpp_add<0x114, 0xf, 0xf, true >(x);  // row_shr:4
    x = dpp_add<0x118, 0xf, 0xf, true >(x);  // row_shr:8
    x = dpp_add<0x142, 0xa, 0xf, false>(x);  // row_bcast:15
    x = dpp_add<0x143, 0xc, 0xf, false>(x);  // row_bcast:31 -> lane63 total
    return x;
}
// 16-lane row sum; result in lane 15 of each row
__device__ __forceinline__ float row_sum15(float x) {
    x = dpp_add<0x111, 0xf, 0xf, true >(x);
    x = dpp_add<0x112, 0xf, 0xf, true >(x);
    x = dpp_add<0x114, 0xf, 0xf, true >(x);
    x = dpp_add<0x118, 0xf, 0xf, true >(x);
    return x;
}

struct SmemT {
    float redPG[32][NLAGS];       // 32 row-partials per lag
    float edges[10][MAXLAG + 1];  // 0:prefP 1:prefPP 2:prefG 3:prefGG (4 unused)
                                  // 5:sufP  6:sufPP  7:sufG  8:sufGG  (9 unused)
    float wsums[8][4];
    float pcc_s[NLAGS];
    float l1part[32];
    float best_pcc, zero_pcc, pen;
    int best_il;
};

__global__ __launch_bounds__(NT, 4) void lagloss_kernel(const float* __restrict__ pred,
                                                        const float* __restrict__ gt,
                                                        float4* __restrict__ ws) {
    __shared__ float lds_p[6240];
    __shared__ float lds_g[6240];
    __shared__ SmemT sm;

    const int b = blockIdx.x;
    const int tid = threadIdx.x;
    const int wid = tid >> 6;
    const int lane = tid & 63;
    const float* __restrict__ prow = pred + (size_t)b * LL;
    const float* __restrict__ grow = gt + (size_t)b * LL;

    // ---- zero the pads: ip in [0,32) and [4128,4160) for both buffers ----
    if (tid < 32) {
        const int m = tid & 7;
        const int ip = ((tid & 8) ? 4128 : 0) + 4 * m;
        const int fi = ip + 4 * (ip >> 3);
        float* buf = (tid < 16) ? lds_p : lds_g;
        *(float4*)&buf[fi] = float4{0.f, 0.f, 0.f, 0.f};
    }

    // ---- stage rows into padded LDS (dense coalesced float4) + full-row sums ----
    const int wb = 4 * tid + 32 + 4 * ((tid + 8) >> 1);
    float ap = 0.f, ag = 0.f, app = 0.f, agg = 0.f;
    #pragma unroll
    for (int it = 0; it < 2; ++it) {
        const int j = tid + NT * it;
        const float4 p4 = ((const float4*)prow)[j];
        const float4 g4 = ((const float4*)grow)[j];
        *(float4*)&lds_p[wb + 3072 * it] = p4;
        *(float4*)&lds_g[wb + 3072 * it] = g4;
        ap += p4.x + p4.y + p4.z + p4.w;
        ag += g4.x + g4.y + g4.z + g4.w;
        app = fmaf(p4.x, p4.x, fmaf(p4.y, p4.y, fmaf(p4.z, p4.z, fmaf(p4.w, p4.w, app))));
        agg = fmaf(g4.x, g4.x, fmaf(g4.y, g4.y, fmaf(g4.z, g4.z, fmaf(g4.w, g4.w, agg))));
    }
    ap = wave_sum63(ap); ag = wave_sum63(ag);
    app = wave_sum63(app); agg = wave_sum63(agg);
    if (lane == 63) {
        sm.wsums[wid][0] = ap; sm.wsums[wid][1] = ag;
        sm.wsums[wid][2] = app; sm.wsums[wid][3] = agg;
    }
    __syncthreads();

    // ---- edge prefix/suffix sums: wave 0 lanes 0..7, one array each ----
    if (wid == 0 && lane < 8) {
        const int a = (lane < 4) ? lane : lane + 1;   // {0,1,2,3,5,6,7,8}
        const int m = a % 5;
        const bool useG = (m >= 2);
        const bool bwd = (a >= 5);
        const bool opSq = (m & 1);
        const float* buf = useG ? lds_g : lds_p;
        float s = 0.f;
        #pragma unroll
        for (int k = 0; k <= MAXLAG; ++k) {
            sm.edges[a][k] = s;
            if (k < MAXLAG) {
                const int i = bwd ? (LL - 1 - k) : k;
                const int ip = i + 32;
                const float x = buf[ip + 4 * (ip >> 3)];
                s += opSq ? x * x : x;
            }
        }
    }

    // ---- g chunk into registers ----
    float gr[CHUNK];
    {
        const int gbase = 12 * tid;
        const float4 a = *(const float4*)&lds_g[gbase + 48];  // fo(0)
        const float4 c = *(const float4*)&lds_g[gbase + 52];  // fo(4)
        gr[0] = a.x; gr[1] = a.y; gr[2] = a.z; gr[3] = a.w;
        gr[4] = c.x; gr[5] = c.y; gr[6] = c.z; gr[7] = c.w;
    }
    const bool isTail = ((tid & 15) == 15);

    // ---- load FULL 48-float window once (12 aligned b128), then all 41 lags
    //      as pure-register FMA + DPP with cross-lag ILP ----
    {
        float pw[48];                        // pw[j] = p[8t - 20 + j], j = 0..47
        const int pbase = 12 * tid;
        #pragma unroll
        for (int k = 0; k < 12; ++k) {
            const int x32 = 12 + 4 * k;      // = (j=4k) - 20 + 32
            const int fo = x32 + 4 * (x32 >> 3);
            const float4 w = *(const float4*)&lds_p[pbase + fo];
            pw[4 * k + 0] = w.x; pw[4 * k + 1] = w.y;
            pw[4 * k + 2] = w.z; pw[4 * k + 3] = w.w;
        }
        #pragma unroll
        for (int il = 0; il < NLAGS; ++il) {
            float s0 = 0.f, s1 = 0.f;
            #pragma unroll
            for (int k = 0; k < CHUNK; k += 2) {
                s0 = fmaf(pw[il + k],     gr[k],     s0);
                s1 = fmaf(pw[il + k + 1], gr[k + 1], s1);
            }
            const float spg = row_sum15(s0 + s1);
            if (isTail) sm.redPG[tid >> 4][il] = spg;
        }
    }
    __syncthreads();

    // ---- per-lag pcc assembly: 41 threads (wave 0), one lag each ----
    if (tid < NLAGS) {
        const int il = tid;
        const int l = il - MAXLAG;
        const int m = l < 0 ? -l : l;
        const float fn = (float)(LL - m);
        float spg = 0.f;
        #pragma unroll
        for (int r = 0; r < 32; ++r) spg += sm.redPG[r][il];
        float Sp = 0.f, Sg = 0.f, Spp = 0.f, Sgg = 0.f;
        #pragma unroll
        for (int w = 0; w < 8; ++w) {
            Sp += sm.wsums[w][0]; Sg += sm.wsums[w][1];
            Spp += sm.wsums[w][2]; Sgg += sm.wsums[w][3];
        }
        float Spw, Sgw, Sppw, Sggw;
        if (l >= 0) {
            Spw  = Sp  - sm.edges[0][m];
            Sppw = Spp - sm.edges[1][m];
            Sgw  = Sg  - sm.edges[7][m];
            Sggw = Sgg - sm.edges[8][m];
        } else {
            Spw  = Sp  - sm.edges[5][m];
            Sppw = Spp - sm.edges[6][m];
            Sgw  = Sg  - sm.edges[2][m];
            Sggw = Sgg - sm.edges[3][m];
        }
        const float num  = spg - Spw * Sgw / fn;
        const float varp = Sppw - Spw * Spw / fn;
        const float varg = Sggw - Sgw * Sgw / fn;
        const float den2 = fmaxf(varp * varg, 1e-12f);
        sm.pcc_s[il] = num / sqrtf(den2);
    }
    __syncthreads();

    // ---- argmax + softmax penalty: wave 0, lane-parallel ----
    if (wid == 0) {
        const float v = (lane < NLAGS) ? sm.pcc_s[lane] : -3.0f;
        float bv = v;
        int bi = lane;
        #pragma unroll
        for (int d = 32; d; d >>= 1) {
            const float ov = __shfl_xor(bv, d, 64);
            const int oi = __shfl_xor(bi, d, 64);
            if (ov > bv || (ov == bv && oi < bi)) { bv = ov; bi = oi; }
        }
        const float e = (lane < NLAGS) ? __expf((v - bv) * (1.0f / TAU)) : 0.0f;
        const float lc = (lane < NLAGS) ? fabsf((float)(lane - MAXLAG)) * (1.0f / MAXLAG) : 0.0f;
        float wsum = e, psum = e * lc;
        #pragma unroll
        for (int d = 32; d; d >>= 1) {
            wsum += __shfl_xor(wsum, d, 64);
            psum += __shfl_xor(psum, d, 64);
        }
        if (lane == 0) {
            sm.best_pcc = bv;
            sm.best_il = bi;
            sm.zero_pcc = sm.pcc_s[MAXLAG];
            sm.pen = psum / wsum;
        }
    }
    __syncthreads();

    // ---- L1 for the single best lag: masked pass over own chunk ----
    {
        const int bl = sm.best_il - MAXLAG;
        const int c0 = tid * CHUNK;
        float sab = 0.f;
        #pragma unroll
        for (int k = 0; k < CHUNK; ++k) {
            const int pi = c0 + k + bl;
            const int ip = pi + 32;
            const float p = lds_p[ip + 4 * (ip >> 3)];  // pads are zero
            const float d = fabsf(p - gr[k]);
            sab += (pi >= 0 && pi < LL) ? d : 0.f;
        }
        sab = row_sum15(sab);
        if (isTail) sm.l1part[tid >> 4] = sab;
    }
    __syncthreads();

    // ---- per-block scalars -> workspace (plain store, no atomics) ----
    if (tid == 0) {
        const int bl = sm.best_il - MAXLAG;
        const int m = bl < 0 ? -bl : bl;
        float sab = 0.f;
        #pragma unroll
        for (int r = 0; r < 32; ++r) sab += sm.l1part[r];
        const float l1 = sab / (float)(LL - m);
        ws[b] = float4{1.0f - sm.best_pcc, l1, 1.0f - sm.zero_pcc, sm.pen};
    }
}

// ---- stage 2: reduce 512 float4 partials -> 4 output scalars ----
__global__ __launch_bounds__(512) void reduce_kernel(const float4* __restrict__ ws,
                                                     float* __restrict__ out) {
    __shared__ float4 part[8];
    const int tid = threadIdx.x;
    const int wid = tid >> 6;
    const int lane = tid & 63;
    const float4 v = ws[tid];
    const float x = wave_sum63(v.x);
    const float y = wave_sum63(v.y);
    const float z = wave_sum63(v.z);
    const float w = wave_sum63(v.w);
    if (lane == 63) part[wid] = float4{x, y, z, w};
    __syncthreads();
    if (tid == 0) {
        float s0 = 0.f, s1 = 0.f, s2 = 0.f, s3 = 0.f;
        #pragma unroll
        for (int i = 0; i < 8; ++i) {
            s0 += part[i].x; s1 += part[i].y; s2 += part[i].z; s3 += part[i].w;
        }
        const float inv = 1.0f / (float)BB;
        out[0] = s0 * inv;
        out[1] = s1 * inv;
        out[2] = s2 * inv;
        out[3] = s3 * inv;
    }
}

extern "C" void kernel_launch(void* const* d_in, const int* in_sizes, int n_in,
                              void* d_out, int out_size, void* d_ws, size_t ws_size,
                              hipStream_t stream) {
    const float* pred = (const float*)d_in[0];
    const float* gt   = (const float*)d_in[1];
    float* out = (float*)d_out;
    float4* ws = (float4*)d_ws;

    lagloss_kernel<<<BB, NT, 0, stream>>>(pred, gt, ws);
    reduce_kernel<<<1, 512, 0, stream>>>(ws, out);
}